// Round 5
// baseline (690.857 us; speedup 1.0000x reference)
//
#include <hip/hip_runtime.h>
#include <hip/hip_bf16.h>
#include <math.h>

// Problem constants (B=2,S=2048 -> T=4096, H=1024, I=2048, E=8, top-2)
#define T_TOK 4096
#define H_DIM 1024
#define I_DIM 2048
#define E_NUM 8

typedef __bf16 bf16x8 __attribute__((ext_vector_type(8)));
typedef float  f32x4  __attribute__((ext_vector_type(4)));

// ---- helpers -------------------------------------------------------------
__device__ inline void gll16(const void* g, void* l) {
    __builtin_amdgcn_global_load_lds(
        (const __attribute__((address_space(1))) void*)g,
        (__attribute__((address_space(3))) void*)l, 16, 0, 0);
}

__device__ inline unsigned short f2bf(float f) {
    union { float f; unsigned u; } v; v.f = f;
    unsigned r = v.u + 0x7FFF + ((v.u >> 16) & 1);   // RNE
    return (unsigned short)(r >> 16);
}

// Stage a 128-row x 32-col bf16 tile (8 KB) into LDS via global_load_lds.
// k-group g_phys holds logical k-group g_phys ^ ((row>>1)&3) (XOR swizzle).
// This exact layout measured 0 LDS bank conflicts (R2).
__device__ inline void stage8k(const unsigned short* gbase, int stride,
                               int k0, char* smbase, int tid, int wv) {
#pragma unroll
    for (int it = 0; it < 2; ++it) {
        int idx = it * 256 + tid;             // 0..511, 16 B each
        int r   = idx >> 2;
        int kg  = (idx & 3) ^ ((r >> 1) & 3);
        gll16(gbase + (size_t)r * stride + k0 + kg * 8,
              smbase + it * 4096 + wv * 1024);
    }
}

__device__ inline bf16x8 frag_ld(const char* smbase, int row, int q) {
    int kg = q ^ ((row >> 1) & 3);
    return *(const bf16x8*)(smbase + row * 64 + kg * 16);
}

// ---------------- Router ----------------
__global__ __launch_bounds__(256) void router_kernel(
    const float* __restrict__ x, const float* __restrict__ gw,
    float* __restrict__ logits_out, int* __restrict__ counts,
    int* __restrict__ tok_list, float* __restrict__ w_list)
{
    int wave = threadIdx.x >> 6;
    int lane = threadIdx.x & 63;
    int t = blockIdx.x * 4 + wave;
    if (t >= T_TOK) return;

    float xs[16];
#pragma unroll
    for (int i = 0; i < 16; ++i) xs[i] = x[(size_t)t * H_DIM + i * 64 + lane];

    float lg[E_NUM];
#pragma unroll
    for (int e = 0; e < E_NUM; ++e) {
        float acc = 0.f;
#pragma unroll
        for (int i = 0; i < 16; ++i) acc += xs[i] * gw[e * H_DIM + i * 64 + lane];
#pragma unroll
        for (int off = 32; off >= 1; off >>= 1) acc += __shfl_xor(acc, off, 64);
        lg[e] = acc;
    }

    if (lane == 0) {
#pragma unroll
        for (int e = 0; e < E_NUM; ++e) logits_out[(size_t)t * E_NUM + e] = lg[e];
        float m = lg[0];
        for (int e = 1; e < E_NUM; ++e) m = fmaxf(m, lg[e]);
        float p[E_NUM]; float s = 0.f;
        for (int e = 0; e < E_NUM; ++e) { p[e] = expf(lg[e] - m); s += p[e]; }
        float invs = 1.f / s;
        for (int e = 0; e < E_NUM; ++e) p[e] *= invs;
        int i0 = 0; float p0 = p[0];
        for (int e = 1; e < E_NUM; ++e) if (p[e] > p0) { p0 = p[e]; i0 = e; }
        int i1 = -1; float p1 = -1.f;
        for (int e = 0; e < E_NUM; ++e) { if (e == i0) continue; if (p[e] > p1) { p1 = p[e]; i1 = e; } }
        float inv = 1.f / (p0 + p1);
        int pos0 = atomicAdd(&counts[i0], 1);
        tok_list[i0 * T_TOK + pos0] = t; w_list[i0 * T_TOK + pos0] = p0 * inv;
        int pos1 = atomicAdd(&counts[i1], 1);
        tok_list[i1 * T_TOK + pos1] = t; w_list[i1 * T_TOK + pos1] = p1 * inv;
    }
}

// ---------------- Padded offsets (128-aligned per expert) ----------------
__global__ void offsets_kernel(const int* __restrict__ counts, int* __restrict__ poff)
{
    if (threadIdx.x == 0 && blockIdx.x == 0) {
        int s = 0;
        for (int e = 0; e < E_NUM; ++e) { poff[e] = s; s += ((counts[e] + 127) >> 7) << 7; }
    }
}

// ---------------- Transpose+convert all 3 weight tensors in one launch ----
__global__ __launch_bounds__(256) void transpose_cvt(
    const float* __restrict__ wg, const float* __restrict__ wu,
    const float* __restrict__ wd,
    unsigned short* __restrict__ wgT, unsigned short* __restrict__ wuT,
    unsigned short* __restrict__ wdT)
{
    int z = blockIdx.z;
    const float* in; unsigned short* outp; int K, N, k0, n0;
    int e = z & 7;
    if (z < 16) {
        K = H_DIM; N = I_DIM;
        in   = (z < 8 ? wg : wu) + (size_t)e * K * N;
        outp = (z < 8 ? wgT : wuT) + (size_t)e * K * N;
        n0 = blockIdx.x * 64; k0 = blockIdx.y * 64;
    } else {
        K = I_DIM; N = H_DIM;
        in   = wd  + (size_t)e * K * N;
        outp = wdT + (size_t)e * K * N;
        k0 = blockIdx.x * 64; n0 = blockIdx.y * 64;
    }
    __shared__ float t[64][65];
    int tid = threadIdx.x;
    {
        int c4 = (tid & 15) * 4, rr = tid >> 4;
#pragma unroll
        for (int it = 0; it < 4; ++it) {
            int r = rr + it * 16;
            float4 v = *(const float4*)(in + (size_t)(k0 + r) * N + n0 + c4);
            t[r][c4] = v.x; t[r][c4 + 1] = v.y; t[r][c4 + 2] = v.z; t[r][c4 + 3] = v.w;
        }
    }
    __syncthreads();
    {
        int nn = tid >> 2, kq = tid & 3;
        unsigned short buf[16];
#pragma unroll
        for (int j = 0; j < 16; ++j) buf[j] = f2bf(t[kq * 16 + j][nn]);
        uint4* dst = (uint4*)(outp + (size_t)(n0 + nn) * K + k0 + kq * 16);
        dst[0] = ((uint4*)buf)[0];
        dst[1] = ((uint4*)buf)[1];
    }
}

// ---------------- Gather x rows -> xg (bf16, padded slots) ----------------
__global__ __launch_bounds__(256) void gather_x(
    const float* __restrict__ x, const int* __restrict__ counts,
    const int* __restrict__ poff, const int* __restrict__ tok_list,
    unsigned short* __restrict__ xg)
{
    int e  = blockIdx.x >> 5;
    int mt = blockIdx.x & 31;
    int cnt = counts[e];
    int m0 = mt * 128;
    if (m0 >= cnt) return;
    int base = poff[e];
    int tid = threadIdx.x;
#pragma unroll 4
    for (int it = 0; it < 64; ++it) {
        int idx = it * 256 + tid;
        int r  = idx >> 7;
        int c8 = idx & 127;
        int m  = m0 + r;
        int mc = (m < cnt) ? m : cnt - 1;
        int t  = tok_list[e * T_TOK + mc];
        const float4* p = (const float4*)(x + (size_t)t * H_DIM + c8 * 8);
        float4 a = p[0], b = p[1];
        unsigned short o[8] = { f2bf(a.x), f2bf(a.y), f2bf(a.z), f2bf(a.w),
                                f2bf(b.x), f2bf(b.y), f2bf(b.z), f2bf(b.w) };
        *(uint4*)(xg + (size_t)(base + m) * H_DIM + c8 * 8) = *(uint4*)o;
    }
}

// ---------------- MLP1: h = silu(X Wg) * (X Wu) --------------------------
// Block tile 128m x 64n (gate+up), waves 2x2 (wave 64m x 32n), BK=64.
// A via double-buffered global_load_lds (2 x 16 KB, two 8K halves each);
// B fragments direct global->reg, issued BEFORE stage (vmcnt is ordered!).
__global__ __launch_bounds__(256, 3) void mlp1_kernel(
    const unsigned short* __restrict__ xg,
    const unsigned short* __restrict__ wgT, const unsigned short* __restrict__ wuT,
    const int* __restrict__ counts, const int* __restrict__ poff,
    unsigned short* __restrict__ hbuf)
{
    int e = blockIdx.z;
    int cnt = counts[e];
    int m0 = blockIdx.y * 128;
    if (m0 >= cnt) return;
    int n0 = blockIdx.x * 64;

    const unsigned short* A = xg + (size_t)(poff[e] + m0) * H_DIM;

    __shared__ char sm[32768];   // 2 buffers x (2 x 8 KB halves)

    int tid = threadIdx.x, lane = tid & 63, wv = tid >> 6;
    int wm = (wv >> 1) * 64, wn = (wv & 1) * 32;
    int q = lane >> 4, rl = lane & 15;

    const unsigned short* Bg = wgT + (size_t)e * I_DIM * H_DIM
                             + (size_t)(n0 + wn + rl) * H_DIM + q * 8;
    const unsigned short* Bu = wuT + (size_t)e * I_DIM * H_DIM
                             + (size_t)(n0 + wn + rl) * H_DIM + q * 8;

    f32x4 accg[4][2], accu[4][2];
#pragma unroll
    for (int i = 0; i < 4; ++i)
#pragma unroll
        for (int j = 0; j < 2; ++j) {
            accg[i][j] = (f32x4){0.f, 0.f, 0.f, 0.f};
            accu[i][j] = (f32x4){0.f, 0.f, 0.f, 0.f};
        }

    stage8k(A, H_DIM, 0,  sm,        tid, wv);
    stage8k(A, H_DIM, 32, sm + 8192, tid, wv);
    __syncthreads();

    for (int k0 = 0; k0 < H_DIM; k0 += 64) {
        char* cur = sm + (((k0 >> 6) & 1) ? 16384 : 0);
        char* nxt = sm + (((k0 >> 6) & 1) ? 0 : 16384);
        bool more = (k0 + 64) < H_DIM;

        // B fragments for THIS step — issue first so vmcnt-wait on them
        // does not drain the stage-next queue.
        bf16x8 bg[2][2], bu[2][2];   // [kk][j]
#pragma unroll
        for (int kk = 0; kk < 2; ++kk)
#pragma unroll
            for (int j = 0; j < 2; ++j) {
                bg[kk][j] = *(const bf16x8*)(Bg + (size_t)j * 16 * H_DIM + k0 + kk * 32);
                bu[kk][j] = *(const bf16x8*)(Bu + (size_t)j * 16 * H_DIM + k0 + kk * 32);
            }

        if (more) {
            stage8k(A, H_DIM, k0 + 64, nxt,        tid, wv);
            stage8k(A, H_DIM, k0 + 96, nxt + 8192, tid, wv);
        }

#pragma unroll
        for (int kk = 0; kk < 2; ++kk) {
            bf16x8 af[4];
#pragma unroll
            for (int i = 0; i < 4; ++i)
                af[i] = frag_ld(cur + kk * 8192, wm + i * 16 + rl, q);
#pragma unroll
            for (int i = 0; i < 4; ++i)
#pragma unroll
                for (int j = 0; j < 2; ++j) {
                    accg[i][j] = __builtin_amdgcn_mfma_f32_16x16x32_bf16(af[i], bg[kk][j], accg[i][j], 0, 0, 0);
                    accu[i][j] = __builtin_amdgcn_mfma_f32_16x16x32_bf16(af[i], bu[kk][j], accu[i][j], 0, 0, 0);
                }
        }
        __syncthreads();
    }

    size_t hrow0 = (size_t)(poff[e] + m0);
#pragma unroll
    for (int i = 0; i < 4; ++i)
#pragma unroll
        for (int p = 0; p < 4; ++p) {
            int row = wm + i * 16 + q * 4 + p;
            unsigned short* orow = hbuf + (hrow0 + row) * I_DIM + n0 + wn + rl;
#pragma unroll
            for (int j = 0; j < 2; ++j) {
                float g = accg[i][j][p], u = accu[i][j][p];
                float hv = g / (1.f + __expf(-g)) * u;
                orow[j * 16] = f2bf(hv);
            }
        }
}

// ---------------- MLP2: out += w * (h Wd) --------------------------------
// Block tile 128m x 128n, waves 2x2 (wave 64x64), BK=64. Same pipeline.
__global__ __launch_bounds__(256, 3) void mlp2_kernel(
    const unsigned short* __restrict__ hbuf,
    const unsigned short* __restrict__ wdT,
    const int* __restrict__ counts, const int* __restrict__ poff,
    const int* __restrict__ tok_list, const float* __restrict__ w_list,
    float* __restrict__ out)
{
    int e = blockIdx.z;
    int cnt = counts[e];
    int m0 = blockIdx.y * 128;
    if (m0 >= cnt) return;
    int n0 = blockIdx.x * 128;

    const unsigned short* A = hbuf + (size_t)(poff[e] + m0) * I_DIM;

    __shared__ char sm[32768];

    int tid = threadIdx.x, lane = tid & 63, wv = tid >> 6;
    int wm = (wv >> 1) * 64, wn = (wv & 1) * 64;
    int q = lane >> 4, rl = lane & 15;

    const unsigned short* B = wdT + (size_t)e * H_DIM * I_DIM
                            + (size_t)(n0 + wn + rl) * I_DIM + q * 8;

    f32x4 acc[4][4];
#pragma unroll
    for (int i = 0; i < 4; ++i)
#pragma unroll
        for (int j = 0; j < 4; ++j) acc[i][j] = (f32x4){0.f, 0.f, 0.f, 0.f};

    stage8k(A, I_DIM, 0,  sm,        tid, wv);
    stage8k(A, I_DIM, 32, sm + 8192, tid, wv);
    __syncthreads();

    for (int k0 = 0; k0 < I_DIM; k0 += 64) {
        char* cur = sm + (((k0 >> 6) & 1) ? 16384 : 0);
        char* nxt = sm + (((k0 >> 6) & 1) ? 0 : 16384);
        bool more = (k0 + 64) < I_DIM;

        bf16x8 bc[2][4];   // [kk][j] — issued before stage
#pragma unroll
        for (int kk = 0; kk < 2; ++kk)
#pragma unroll
            for (int j = 0; j < 4; ++j)
                bc[kk][j] = *(const bf16x8*)(B + (size_t)j * 16 * I_DIM + k0 + kk * 32);

        if (more) {
            stage8k(A, I_DIM, k0 + 64, nxt,        tid, wv);
            stage8k(A, I_DIM, k0 + 96, nxt + 8192, tid, wv);
        }

#pragma unroll
        for (int kk = 0; kk < 2; ++kk) {
            bf16x8 af[4];
#pragma unroll
            for (int i = 0; i < 4; ++i)
                af[i] = frag_ld(cur + kk * 8192, wm + i * 16 + rl, q);
#pragma unroll
            for (int i = 0; i < 4; ++i)
#pragma unroll
                for (int j = 0; j < 4; ++j)
                    acc[i][j] = __builtin_amdgcn_mfma_f32_16x16x32_bf16(af[i], bc[kk][j], acc[i][j], 0, 0, 0);
        }
        __syncthreads();
    }

#pragma unroll
    for (int i = 0; i < 4; ++i)
#pragma unroll
        for (int p = 0; p < 4; ++p) {
            int m = m0 + wm + i * 16 + q * 4 + p;
            if (m < cnt) {
                int   t = tok_list[e * T_TOK + m];
                float w = w_list[e * T_TOK + m];
                float* op = out + (size_t)t * H_DIM + n0 + wn + rl;
#pragma unroll
                for (int j = 0; j < 4; ++j) atomicAdd(op + j * 16, w * acc[i][j][p]);
            }
        }
}

extern "C" void kernel_launch(void* const* d_in, const int* in_sizes, int n_in,
                              void* d_out, int out_size, void* d_ws, size_t ws_size,
                              hipStream_t stream)
{
    const float* x      = (const float*)d_in[0];   // [T,H]
    const float* gate_w = (const float*)d_in[1];   // [E,H]
    const float* w_gate = (const float*)d_in[2];   // [E,H,I]
    const float* w_up   = (const float*)d_in[3];   // [E,H,I]
    const float* w_down = (const float*)d_in[4];   // [E,I,H]

    float* out        = (float*)d_out;                 // [T,H]
    float* logits_out = out + (size_t)T_TOK * H_DIM;   // [T,E]

    char* ws = (char*)d_ws;
    int*   counts   = (int*)ws;
    int*   poff     = (int*)(ws + 64);
    int*   tok_list = (int*)(ws + 1024);
    float* w_list   = (float*)(ws + 1024 + E_NUM * T_TOK * 4);

    const size_t XG_ROWS = 9216;                       // 8192 + 8*128 padding
    const size_t OFF_XG = 1u << 20;
    const size_t OFF_HB = OFF_XG + XG_ROWS * H_DIM * 2;
    const size_t OFF_WG = OFF_HB + XG_ROWS * I_DIM * 2;
    const size_t OFF_WU = OFF_WG + (size_t)E_NUM * H_DIM * I_DIM * 2;
    const size_t OFF_WD = OFF_WU + (size_t)E_NUM * H_DIM * I_DIM * 2;

    unsigned short* xg   = (unsigned short*)(ws + OFF_XG);
    unsigned short* hbuf = (unsigned short*)(ws + OFF_HB);
    unsigned short* wgT  = (unsigned short*)(ws + OFF_WG);  // [E][I][H]
    unsigned short* wuT  = (unsigned short*)(ws + OFF_WU);  // [E][I][H]
    unsigned short* wdT  = (unsigned short*)(ws + OFF_WD);  // [E][H][I]

    hipMemsetAsync(counts, 0, E_NUM * sizeof(int), stream);
    hipMemsetAsync(out, 0, (size_t)T_TOK * H_DIM * sizeof(float), stream);

    router_kernel<<<T_TOK / 4, 256, 0, stream>>>(x, gate_w, logits_out, counts, tok_list, w_list);
    offsets_kernel<<<1, 64, 0, stream>>>(counts, poff);

    dim3 gt(32, 16, 24);
    transpose_cvt<<<gt, 256, 0, stream>>>(w_gate, w_up, w_down, wgT, wuT, wdT);

    gather_x<<<E_NUM * 32, 256, 0, stream>>>(x, counts, poff, tok_list, xg);

    dim3 g1(I_DIM / 64, T_TOK / 128, E_NUM);
    mlp1_kernel<<<g1, 256, 0, stream>>>(xg, wgT, wuT, counts, poff, hbuf);

    dim3 g2(H_DIM / 128, T_TOK / 128, E_NUM);
    mlp2_kernel<<<g2, 256, 0, stream>>>(hbuf, wdT, counts, poff, tok_list, w_list, out);
}

// Round 6
// 559.492 us; speedup vs baseline: 1.2348x; 1.2348x over previous
//
#include <hip/hip_runtime.h>
#include <hip/hip_bf16.h>
#include <math.h>

// Problem constants (B=2,S=2048 -> T=4096, H=1024, I=2048, E=8, top-2)
#define T_TOK 4096
#define H_DIM 1024
#define I_DIM 2048
#define E_NUM 8

typedef __bf16 bf16x8 __attribute__((ext_vector_type(8)));
typedef float  f32x4  __attribute__((ext_vector_type(4)));

// ---- helpers -------------------------------------------------------------
__device__ inline void gll16(const void* g, void* l) {
    __builtin_amdgcn_global_load_lds(
        (const __attribute__((address_space(1))) void*)g,
        (__attribute__((address_space(3))) void*)l, 16, 0, 0);
}

__device__ inline unsigned short f2bf(float f) {
    union { float f; unsigned u; } v; v.f = f;
    unsigned r = v.u + 0x7FFF + ((v.u >> 16) & 1);   // RNE
    return (unsigned short)(r >> 16);
}

__device__ inline float bf2f(unsigned short u) {
    union { unsigned u; float f; } v; v.u = ((unsigned)u) << 16;
    return v.f;
}

// Stage a 128-row x 32-col bf16 tile (8 KB) into LDS via global_load_lds.
// k-group g_phys holds logical k-group g_phys ^ ((row>>1)&3) (XOR swizzle).
// This exact layout measured 0 LDS bank conflicts (R2/R4/R5).
__device__ inline void stage8k(const unsigned short* gbase, int stride,
                               int k0, char* smbase, int tid, int wv) {
#pragma unroll
    for (int it = 0; it < 2; ++it) {
        int idx = it * 256 + tid;             // 0..511, 16 B each
        int r   = idx >> 2;
        int kg  = (idx & 3) ^ ((r >> 1) & 3);
        gll16(gbase + (size_t)r * stride + k0 + kg * 8,
              smbase + it * 4096 + wv * 1024);
    }
}

// Stage a 64-row x 32-col bf16 tile (4 KB): one gll16 per thread.
__device__ inline void stage4k(const unsigned short* gbase, int stride,
                               int k0, char* smbase, int tid) {
    int r  = tid >> 2;                        // 0..63
    int kg = (tid & 3) ^ ((r >> 1) & 3);
    gll16(gbase + (size_t)r * stride + k0 + kg * 8,
          smbase + (tid >> 6) * 1024);        // wave-uniform base + lane*16
}

__device__ inline bf16x8 frag_ld(const char* smbase, int row, int q) {
    int kg = q ^ ((row >> 1) & 3);
    return *(const bf16x8*)(smbase + row * 64 + kg * 16);
}

// ---------------- Router ----------------
// tok_list entries encode token*2 + slot (slot 0 = primary expert choice).
__global__ __launch_bounds__(256) void router_kernel(
    const float* __restrict__ x, const float* __restrict__ gw,
    float* __restrict__ logits_out, int* __restrict__ counts,
    int* __restrict__ tok_list, float* __restrict__ w_list)
{
    int wave = threadIdx.x >> 6;
    int lane = threadIdx.x & 63;
    int t = blockIdx.x * 4 + wave;
    if (t >= T_TOK) return;

    float xs[16];
#pragma unroll
    for (int i = 0; i < 16; ++i) xs[i] = x[(size_t)t * H_DIM + i * 64 + lane];

    float lg[E_NUM];
#pragma unroll
    for (int e = 0; e < E_NUM; ++e) {
        float acc = 0.f;
#pragma unroll
        for (int i = 0; i < 16; ++i) acc += xs[i] * gw[e * H_DIM + i * 64 + lane];
#pragma unroll
        for (int off = 32; off >= 1; off >>= 1) acc += __shfl_xor(acc, off, 64);
        lg[e] = acc;
    }

    if (lane == 0) {
#pragma unroll
        for (int e = 0; e < E_NUM; ++e) logits_out[(size_t)t * E_NUM + e] = lg[e];
        float m = lg[0];
        for (int e = 1; e < E_NUM; ++e) m = fmaxf(m, lg[e]);
        float p[E_NUM]; float s = 0.f;
        for (int e = 0; e < E_NUM; ++e) { p[e] = expf(lg[e] - m); s += p[e]; }
        float invs = 1.f / s;
        for (int e = 0; e < E_NUM; ++e) p[e] *= invs;
        int i0 = 0; float p0 = p[0];
        for (int e = 1; e < E_NUM; ++e) if (p[e] > p0) { p0 = p[e]; i0 = e; }
        int i1 = -1; float p1 = -1.f;
        for (int e = 0; e < E_NUM; ++e) { if (e == i0) continue; if (p[e] > p1) { p1 = p[e]; i1 = e; } }
        float inv = 1.f / (p0 + p1);
        int pos0 = atomicAdd(&counts[i0], 1);
        tok_list[i0 * T_TOK + pos0] = t * 2 + 0; w_list[i0 * T_TOK + pos0] = p0 * inv;
        int pos1 = atomicAdd(&counts[i1], 1);
        tok_list[i1 * T_TOK + pos1] = t * 2 + 1; w_list[i1 * T_TOK + pos1] = p1 * inv;
    }
}

// ---------------- Padded offsets (128-aligned per expert) ----------------
__global__ void offsets_kernel(const int* __restrict__ counts, int* __restrict__ poff)
{
    if (threadIdx.x == 0 && blockIdx.x == 0) {
        int s = 0;
        for (int e = 0; e < E_NUM; ++e) { poff[e] = s; s += ((counts[e] + 127) >> 7) << 7; }
    }
}

// ---------------- Transpose+convert all 3 weight tensors in one launch ----
__global__ __launch_bounds__(256) void transpose_cvt(
    const float* __restrict__ wg, const float* __restrict__ wu,
    const float* __restrict__ wd,
    unsigned short* __restrict__ wgT, unsigned short* __restrict__ wuT,
    unsigned short* __restrict__ wdT)
{
    int z = blockIdx.z;
    const float* in; unsigned short* outp; int K, N, k0, n0;
    int e = z & 7;
    if (z < 16) {
        K = H_DIM; N = I_DIM;
        in   = (z < 8 ? wg : wu) + (size_t)e * K * N;
        outp = (z < 8 ? wgT : wuT) + (size_t)e * K * N;
        n0 = blockIdx.x * 64; k0 = blockIdx.y * 64;
    } else {
        K = I_DIM; N = H_DIM;
        in   = wd  + (size_t)e * K * N;
        outp = wdT + (size_t)e * K * N;
        k0 = blockIdx.x * 64; n0 = blockIdx.y * 64;
    }
    __shared__ float t[64][65];
    int tid = threadIdx.x;
    {
        int c4 = (tid & 15) * 4, rr = tid >> 4;
#pragma unroll
        for (int it = 0; it < 4; ++it) {
            int r = rr + it * 16;
            float4 v = *(const float4*)(in + (size_t)(k0 + r) * N + n0 + c4);
            t[r][c4] = v.x; t[r][c4 + 1] = v.y; t[r][c4 + 2] = v.z; t[r][c4 + 3] = v.w;
        }
    }
    __syncthreads();
    {
        int nn = tid >> 2, kq = tid & 3;
        unsigned short buf[16];
#pragma unroll
        for (int j = 0; j < 16; ++j) buf[j] = f2bf(t[kq * 16 + j][nn]);
        uint4* dst = (uint4*)(outp + (size_t)(n0 + nn) * K + k0 + kq * 16);
        dst[0] = ((uint4*)buf)[0];
        dst[1] = ((uint4*)buf)[1];
    }
}

// ---------------- Gather x rows -> xg (bf16, padded slots) ----------------
__global__ __launch_bounds__(256) void gather_x(
    const float* __restrict__ x, const int* __restrict__ counts,
    const int* __restrict__ poff, const int* __restrict__ tok_list,
    unsigned short* __restrict__ xg)
{
    int e  = blockIdx.x >> 5;
    int mt = blockIdx.x & 31;
    int cnt = counts[e];
    int m0 = mt * 128;
    if (m0 >= cnt) return;
    int base = poff[e];
    int tid = threadIdx.x;
#pragma unroll 4
    for (int it = 0; it < 64; ++it) {
        int idx = it * 256 + tid;
        int r  = idx >> 7;
        int c8 = idx & 127;
        int m  = m0 + r;
        int mc = (m < cnt) ? m : cnt - 1;
        int t  = tok_list[e * T_TOK + mc] >> 1;
        const float4* p = (const float4*)(x + (size_t)t * H_DIM + c8 * 8);
        float4 a = p[0], b = p[1];
        unsigned short o[8] = { f2bf(a.x), f2bf(a.y), f2bf(a.z), f2bf(a.w),
                                f2bf(b.x), f2bf(b.y), f2bf(b.z), f2bf(b.w) };
        *(uint4*)(xg + (size_t)(base + m) * H_DIM + c8 * 8) = *(uint4*)o;
    }
}

// ---------------- MLP1: h = silu(X Wg) * (X Wu) --------------------------
// Block tile 128m x 64n fused, all-LDS (A 8K + Bg 4K + Bu 4K per BK=32 step,
// double-buffered). Waves 2x2; wave tile 64m x 32n per tensor.
// m97 ratios: 16 MFMA : 8 ds_read_b128 : 16 KB stage per wave-step.
__global__ __launch_bounds__(256, 3) void mlp1_kernel(
    const unsigned short* __restrict__ xg,
    const unsigned short* __restrict__ wgT, const unsigned short* __restrict__ wuT,
    const int* __restrict__ counts, const int* __restrict__ poff,
    unsigned short* __restrict__ hbuf)
{
    int e = blockIdx.z;
    int cnt = counts[e];
    int m0 = blockIdx.y * 128;
    if (m0 >= cnt) return;
    int n0 = blockIdx.x * 64;

    const unsigned short* A  = xg  + (size_t)(poff[e] + m0) * H_DIM;
    const unsigned short* Bg = wgT + (size_t)e * I_DIM * H_DIM + (size_t)n0 * H_DIM;
    const unsigned short* Bu = wuT + (size_t)e * I_DIM * H_DIM + (size_t)n0 * H_DIM;

    __shared__ char sm[32768];   // 2 buffers x (A 8K | Bg 4K | Bu 4K)

    int tid = threadIdx.x, lane = tid & 63, wv = tid >> 6;
    int wm = (wv >> 1) * 64, wn = (wv & 1) * 32;
    int q = lane >> 4, rl = lane & 15;

    f32x4 accg[4][2], accu[4][2];
#pragma unroll
    for (int i = 0; i < 4; ++i)
#pragma unroll
        for (int j = 0; j < 2; ++j) {
            accg[i][j] = (f32x4){0.f, 0.f, 0.f, 0.f};
            accu[i][j] = (f32x4){0.f, 0.f, 0.f, 0.f};
        }

    stage8k(A,  H_DIM, 0, sm,         tid, wv);
    stage4k(Bg, H_DIM, 0, sm + 8192,  tid);
    stage4k(Bu, H_DIM, 0, sm + 12288, tid);
    __syncthreads();

    for (int k0 = 0; k0 < H_DIM; k0 += 32) {
        char* cur = sm + ((k0 >> 5) & 1) * 16384;
        char* nxt = sm + (1 - ((k0 >> 5) & 1)) * 16384;
        bool more = (k0 + 32) < H_DIM;
        if (more) {
            stage8k(A,  H_DIM, k0 + 32, nxt,         tid, wv);
            stage4k(Bg, H_DIM, k0 + 32, nxt + 8192,  tid);
            stage4k(Bu, H_DIM, k0 + 32, nxt + 12288, tid);
        }

        bf16x8 af[4], bg[2], bu[2];
#pragma unroll
        for (int i = 0; i < 4; ++i) af[i] = frag_ld(cur, wm + i * 16 + rl, q);
#pragma unroll
        for (int j = 0; j < 2; ++j) {
            bg[j] = frag_ld(cur + 8192,  wn + j * 16 + rl, q);
            bu[j] = frag_ld(cur + 12288, wn + j * 16 + rl, q);
        }
#pragma unroll
        for (int i = 0; i < 4; ++i)
#pragma unroll
            for (int j = 0; j < 2; ++j) {
                accg[i][j] = __builtin_amdgcn_mfma_f32_16x16x32_bf16(af[i], bg[j], accg[i][j], 0, 0, 0);
                accu[i][j] = __builtin_amdgcn_mfma_f32_16x16x32_bf16(af[i], bu[j], accu[i][j], 0, 0, 0);
            }
        __syncthreads();
    }

    size_t hrow0 = (size_t)(poff[e] + m0);
#pragma unroll
    for (int i = 0; i < 4; ++i)
#pragma unroll
        for (int p = 0; p < 4; ++p) {
            int row = wm + i * 16 + q * 4 + p;
            unsigned short* orow = hbuf + (hrow0 + row) * I_DIM + n0 + wn + rl;
#pragma unroll
            for (int j = 0; j < 2; ++j) {
                float g = accg[i][j][p], u = accu[i][j][p];
                float hv = g / (1.f + __expf(-g)) * u;
                orow[j * 16] = f2bf(hv);
            }
        }
}

// ---------------- MLP2: y[slot] = w * (h Wd) (no atomics) -----------------
// Block tile 128m x 64n, all-LDS (A 8K + B 4K per BK=32 step, dbuf).
// Waves 2x2; wave tile 64m x 32n; acc 32 AGPR -> 4 waves/SIMD.
__global__ __launch_bounds__(256, 3) void mlp2_kernel(
    const unsigned short* __restrict__ hbuf,
    const unsigned short* __restrict__ wdT,
    const int* __restrict__ counts, const int* __restrict__ poff,
    const int* __restrict__ tok_list, const float* __restrict__ w_list,
    unsigned short* __restrict__ y)
{
    int e = blockIdx.z;
    int cnt = counts[e];
    int m0 = blockIdx.y * 128;
    if (m0 >= cnt) return;
    int n0 = blockIdx.x * 64;

    const unsigned short* A = hbuf + (size_t)(poff[e] + m0) * I_DIM;
    const unsigned short* B = wdT  + (size_t)e * H_DIM * I_DIM + (size_t)n0 * I_DIM;

    __shared__ char sm[24576];   // 2 buffers x (A 8K | B 4K)

    int tid = threadIdx.x, lane = tid & 63, wv = tid >> 6;
    int wm = (wv >> 1) * 64, wn = (wv & 1) * 32;
    int q = lane >> 4, rl = lane & 15;

    f32x4 acc[4][2];
#pragma unroll
    for (int i = 0; i < 4; ++i)
#pragma unroll
        for (int j = 0; j < 2; ++j) acc[i][j] = (f32x4){0.f, 0.f, 0.f, 0.f};

    stage8k(A, I_DIM, 0, sm,        tid, wv);
    stage4k(B, I_DIM, 0, sm + 8192, tid);
    __syncthreads();

    for (int k0 = 0; k0 < I_DIM; k0 += 32) {
        char* cur = sm + ((k0 >> 5) & 1) * 12288;
        char* nxt = sm + (1 - ((k0 >> 5) & 1)) * 12288;
        bool more = (k0 + 32) < I_DIM;
        if (more) {
            stage8k(A, I_DIM, k0 + 32, nxt,        tid, wv);
            stage4k(B, I_DIM, k0 + 32, nxt + 8192, tid);
        }

        bf16x8 af[4], bf[2];
#pragma unroll
        for (int i = 0; i < 4; ++i) af[i] = frag_ld(cur, wm + i * 16 + rl, q);
#pragma unroll
        for (int j = 0; j < 2; ++j) bf[j] = frag_ld(cur + 8192, wn + j * 16 + rl, q);
#pragma unroll
        for (int i = 0; i < 4; ++i)
#pragma unroll
            for (int j = 0; j < 2; ++j)
                acc[i][j] = __builtin_amdgcn_mfma_f32_16x16x32_bf16(af[i], bf[j], acc[i][j], 0, 0, 0);
        __syncthreads();
    }

#pragma unroll
    for (int i = 0; i < 4; ++i)
#pragma unroll
        for (int p = 0; p < 4; ++p) {
            int m = m0 + wm + i * 16 + q * 4 + p;
            if (m < cnt) {
                int   tv = tok_list[e * T_TOK + m];
                int   t  = tv >> 1, sl = tv & 1;
                float w  = w_list[e * T_TOK + m];
                unsigned short* op = y + ((size_t)sl * T_TOK + t) * H_DIM + n0 + wn + rl;
#pragma unroll
                for (int j = 0; j < 2; ++j) op[j * 16] = f2bf(w * acc[i][j][p]);
            }
        }
}

// ---------------- Combine: out = y[0] + y[1] ------------------------------
__global__ __launch_bounds__(256) void combine_kernel(
    const unsigned short* __restrict__ y, float* __restrict__ out)
{
    size_t idx = ((size_t)blockIdx.x * 256 + threadIdx.x) * 8;
    uint4 a = *(const uint4*)(y + idx);
    uint4 b = *(const uint4*)(y + (size_t)T_TOK * H_DIM + idx);
    const unsigned short* pa = (const unsigned short*)&a;
    const unsigned short* pb = (const unsigned short*)&b;
    float r[8];
#pragma unroll
    for (int j = 0; j < 8; ++j) r[j] = bf2f(pa[j]) + bf2f(pb[j]);
    *(float4*)(out + idx)     = (float4){r[0], r[1], r[2], r[3]};
    *(float4*)(out + idx + 4) = (float4){r[4], r[5], r[6], r[7]};
}

extern "C" void kernel_launch(void* const* d_in, const int* in_sizes, int n_in,
                              void* d_out, int out_size, void* d_ws, size_t ws_size,
                              hipStream_t stream)
{
    const float* x      = (const float*)d_in[0];   // [T,H]
    const float* gate_w = (const float*)d_in[1];   // [E,H]
    const float* w_gate = (const float*)d_in[2];   // [E,H,I]
    const float* w_up   = (const float*)d_in[3];   // [E,H,I]
    const float* w_down = (const float*)d_in[4];   // [E,I,H]

    float* out        = (float*)d_out;                 // [T,H]
    float* logits_out = out + (size_t)T_TOK * H_DIM;   // [T,E]

    char* ws = (char*)d_ws;
    int*   counts   = (int*)ws;
    int*   poff     = (int*)(ws + 64);
    int*   tok_list = (int*)(ws + 1024);
    float* w_list   = (float*)(ws + 1024 + E_NUM * T_TOK * 4);

    const size_t XG_ROWS = 9216;                       // 8192 + 8*128 padding
    const size_t OFF_XG = 1u << 20;
    const size_t OFF_HB = OFF_XG + XG_ROWS * H_DIM * 2;
    const size_t OFF_WG = OFF_HB + XG_ROWS * I_DIM * 2;
    const size_t OFF_WU = OFF_WG + (size_t)E_NUM * H_DIM * I_DIM * 2;
    const size_t OFF_WD = OFF_WU + (size_t)E_NUM * H_DIM * I_DIM * 2;

    unsigned short* xg   = (unsigned short*)(ws + OFF_XG);
    unsigned short* hbuf = (unsigned short*)(ws + OFF_HB);
    unsigned short* wgT  = (unsigned short*)(ws + OFF_WG);  // [E][I][H]
    unsigned short* wuT  = (unsigned short*)(ws + OFF_WU);  // [E][I][H]
    unsigned short* wdT  = (unsigned short*)(ws + OFF_WD);  // [E][H][I]
    // y[2][T][H] bf16 (16.8 MB) aliases xg (18.9 MB): xg is dead after mlp1.
    unsigned short* ybuf = xg;

    hipMemsetAsync(counts, 0, E_NUM * sizeof(int), stream);

    router_kernel<<<T_TOK / 4, 256, 0, stream>>>(x, gate_w, logits_out, counts, tok_list, w_list);
    offsets_kernel<<<1, 64, 0, stream>>>(counts, poff);

    dim3 gt(32, 16, 24);
    transpose_cvt<<<gt, 256, 0, stream>>>(w_gate, w_up, w_down, wgT, wuT, wdT);

    gather_x<<<E_NUM * 32, 256, 0, stream>>>(x, counts, poff, tok_list, xg);

    dim3 g1(I_DIM / 64, T_TOK / 128, E_NUM);
    mlp1_kernel<<<g1, 256, 0, stream>>>(xg, wgT, wuT, counts, poff, hbuf);

    dim3 g2(H_DIM / 64, T_TOK / 128, E_NUM);
    mlp2_kernel<<<g2, 256, 0, stream>>>(hbuf, wdT, counts, poff, tok_list, w_list, ybuf);

    combine_kernel<<<(T_TOK * H_DIM) / (256 * 8), 256, 0, stream>>>(ybuf, out);
}